// Round 1
// baseline (8510.847 us; speedup 1.0000x reference)
//
#include <hip/hip_runtime.h>
#include <cstdint>
#include <cstddef>

typedef _Float16 f16x8 __attribute__((ext_vector_type(8)));
typedef float f32x4 __attribute__((ext_vector_type(4)));

#define Bdim 128
#define Tdim 512
#define Ddim 512
#define Hdim 1024
#define H3 3072

// ---------------------------------------------------------------------------
// Pack fp32 weight matrix W[K][3072] into fp16 MFMA B-fragment tiles:
// P[((nt*KT + kt)*64 + lane)*8 + i] = W[(kt*32 + (lane>>4)*8 + i)*3072 + nt*16 + (lane&15)]
// (layout for v_mfma_f32_16x16x32_f16 B operand: b[i] = B[k=(l>>4)*8+i][n=l&15])
// ---------------------------------------------------------------------------
__global__ __launch_bounds__(256) void pack_w_kernel(const float* __restrict__ W,
                                                     _Float16* __restrict__ P, int KT) {
  int u = blockIdx.x * 256 + threadIdx.x;
  int lane = u & 63;
  int kt = (u >> 6) & (KT - 1);
  int nt = (u >> 6) / KT;
  int n = (nt << 4) + (lane & 15);
  int k0 = (kt << 5) + ((lane >> 4) << 3);
  const float* src = W + (size_t)k0 * H3 + n;
  f16x8 v;
#pragma unroll
  for (int i = 0; i < 8; ++i) v[i] = (_Float16)src[(size_t)i * H3];
  *(f16x8*)(P + (size_t)u * 8) = v;
}

// ---------------------------------------------------------------------------
// xi chunk GEMM: xi[tl][b][n] = x[b][tbase+tl][:] @ Wi[:, n] + bi[n]
// grid: (Tc*2, 24), block 256 (4 waves, 2x2).  wg tile: 64 rows x 128 cols.
// A loaded direct from fp32 x (8 consecutive floats/lane), B from WiP fragments.
// ---------------------------------------------------------------------------
__global__ __launch_bounds__(256) void gemm_xi_kernel(const float* __restrict__ x,
                                                      const _Float16* __restrict__ WiP,
                                                      const float* __restrict__ bi,
                                                      float* __restrict__ xi, int tbase) {
  const int w = threadIdx.x >> 6, lane = threadIdx.x & 63;
  const int wm = w >> 1, wn = w & 1;
  const int bx = blockIdx.x, by = blockIdx.y;
  const int rbase = bx * 64 + wm * 32;

  f32x4 acc[2][4] = {};

  const int kA = (lane >> 4) << 3;
  const float* xrow[2];
#pragma unroll
  for (int mt2 = 0; mt2 < 2; ++mt2) {
    int row = rbase + mt2 * 16 + (lane & 15);
    int b = row & (Bdim - 1), tl = row >> 7;
    xrow[mt2] = x + ((size_t)b * Tdim + (tbase + tl)) * Ddim + kA;
  }
  const int nt0 = by * 8 + wn * 4;

  for (int kt = 0; kt < 16; ++kt) {
    f16x8 a[2];
#pragma unroll
    for (int mt2 = 0; mt2 < 2; ++mt2) {
      const float* p = xrow[mt2] + kt * 32;
      float4 lo = *(const float4*)p;
      float4 hi = *(const float4*)(p + 4);
      f16x8 v;
      v[0] = (_Float16)lo.x; v[1] = (_Float16)lo.y; v[2] = (_Float16)lo.z; v[3] = (_Float16)lo.w;
      v[4] = (_Float16)hi.x; v[5] = (_Float16)hi.y; v[6] = (_Float16)hi.z; v[7] = (_Float16)hi.w;
      a[mt2] = v;
    }
#pragma unroll
    for (int nt4 = 0; nt4 < 4; ++nt4) {
      const int nt = nt0 + nt4;
      f16x8 bf = *(const f16x8*)(WiP + (((size_t)nt * 16 + kt) * 64 + lane) * 8);
#pragma unroll
      for (int mt2 = 0; mt2 < 2; ++mt2)
        acc[mt2][nt4] = __builtin_amdgcn_mfma_f32_16x16x32_f16(a[mt2], bf, acc[mt2][nt4], 0, 0, 0);
    }
  }

  // epilogue: C/D layout col = lane&15, row = (lane>>4)*4 + reg
#pragma unroll
  for (int mt2 = 0; mt2 < 2; ++mt2) {
    const int rowb = rbase + mt2 * 16 + ((lane >> 4) << 2);
#pragma unroll
    for (int nt4 = 0; nt4 < 4; ++nt4) {
      const int n = ((nt0 + nt4) << 4) + (lane & 15);
      const float biv = bi[n];
#pragma unroll
      for (int reg = 0; reg < 4; ++reg) {
        const int row = rowb + reg;
        const int b = row & (Bdim - 1), tl = row >> 7;
        xi[((size_t)tl * Bdim + b) * H3 + n] = acc[mt2][nt4][reg] + biv;
      }
    }
  }
}

// ---------------------------------------------------------------------------
// One GRU timestep.  grid (64, 2), block 256 (4 waves).
// wg.x owns h-columns j0=wg.x*16 for all 3 gates; wg.y picks row half.
// wave w handles m-tile mtg = wg.y*4 + w (16 rows).
// Reads h as prepacked fp16 A-fragments, Wh as prepacked B-fragments.
// Writes hy to fp32 buffer (or d_out on last step) and to the fp16 A-packed
// buffer for the next step.
// ---------------------------------------------------------------------------
__global__ __launch_bounds__(256) void gru_step_kernel(
    const _Float16* __restrict__ WhP, const _Float16* __restrict__ hPs,
    const float* __restrict__ hFs, const float* __restrict__ xi,
    const float* __restrict__ bh,
    float* __restrict__ hFd, _Float16* __restrict__ hPd, int tl) {
  const int wg = blockIdx.x;       // 0..63 column group
  const int wgm = blockIdx.y;      // 0..1 row half
  const int w = threadIdx.x >> 6;
  const int lane = threadIdx.x & 63;
  const int mtg = wgm * 4 + w;     // 0..7 m-tile
  const int j0 = wg << 4;

  f32x4 acc[3] = {};

  const _Float16* aP = hPs + ((size_t)mtg * 64 + lane) * 8;
  const _Float16* bP0 = WhP + (((size_t)(0 * 64 + wg) * 32) * 64 + lane) * 8;
  const _Float16* bP1 = WhP + (((size_t)(1 * 64 + wg) * 32) * 64 + lane) * 8;
  const _Float16* bP2 = WhP + (((size_t)(2 * 64 + wg) * 32) * 64 + lane) * 8;

#pragma unroll 4
  for (int kt = 0; kt < 32; ++kt) {
    f16x8 a = *(const f16x8*)(aP + (size_t)kt * (8 * 64 * 8));
    f16x8 b0 = *(const f16x8*)(bP0 + (size_t)kt * (64 * 8));
    f16x8 b1 = *(const f16x8*)(bP1 + (size_t)kt * (64 * 8));
    f16x8 b2 = *(const f16x8*)(bP2 + (size_t)kt * (64 * 8));
    acc[0] = __builtin_amdgcn_mfma_f32_16x16x32_f16(a, b0, acc[0], 0, 0, 0);
    acc[1] = __builtin_amdgcn_mfma_f32_16x16x32_f16(a, b1, acc[1], 0, 0, 0);
    acc[2] = __builtin_amdgcn_mfma_f32_16x16x32_f16(a, b2, acc[2], 0, 0, 0);
  }

  const int j = j0 + (lane & 15);
  const float bhr = bh[j], bhz = bh[Hdim + j], bhn = bh[2 * Hdim + j];
  // pack-write address pieces: element (b, j) -> ktp=j>>5, lane'=(b&15)+16*((j&31)>>3), i=j&7
  const int lanehi = ((wg & 1) << 1) + ((lane & 15) >> 3);
  const int ip = lane & 7;
  const int ktp = wg >> 1;
  const int rbase = (mtg << 4) + ((lane >> 4) << 2);

#pragma unroll
  for (int reg = 0; reg < 4; ++reg) {
    const int b = rbase + reg;
    const float* xr = xi + ((size_t)tl * Bdim + b) * H3 + j;
    const float xirv = xr[0], xizv = xr[Hdim], xinv = xr[2 * Hdim];
    const float whr = acc[0][reg] + bhr;
    const float whz = acc[1][reg] + bhz;
    const float whn = acc[2][reg] + bhn;
    const float hprev = hFs[(size_t)b * Hdim + j];
    const float r = 1.f / (1.f + __expf(-(xirv + whr)));
    const float z = 1.f / (1.f + __expf(-(xizv + whz)));
    const float nn = tanhf(xinv + r * whn);
    const float hy = z * nn + (1.f - z) * hprev;
    hFd[(size_t)b * Hdim + j] = hy;
    const int laneP = (b & 15) + (lanehi << 4);
    hPd[(((size_t)ktp * 8 + mtg) * 64 + laneP) * 8 + ip] = (_Float16)hy;
  }
}

// ---------------------------------------------------------------------------
extern "C" void kernel_launch(void* const* d_in, const int* in_sizes, int n_in,
                              void* d_out, int out_size, void* d_ws, size_t ws_size,
                              hipStream_t stream) {
  const float* x  = (const float*)d_in[0];
  const float* Wi = (const float*)d_in[1];
  const float* bi = (const float*)d_in[2];
  const float* Wh = (const float*)d_in[3];
  const float* bh = (const float*)d_in[4];
  float* out = (float*)d_out;
  char* ws = (char*)d_ws;

  // workspace layout (bytes)
  _Float16* WiP = (_Float16*)(ws + 0);          // 3,145,728 B
  _Float16* WhP = (_Float16*)(ws + 3145728);    // 6,291,456 B
  _Float16* hP0 = (_Float16*)(ws + 9437184);    //   262,144 B
  _Float16* hP1 = (_Float16*)(ws + 9699328);    //   262,144 B
  float*    hF0 = (float*)(ws + 9961472);       //   524,288 B
  float*    hF1 = (float*)(ws + 10485760);      //   524,288 B
  float*    xiC = (float*)(ws + 11010048);      // Tc*1,572,864 B
  const size_t fixed = 11010048;

  int Tc = 512;
  while (Tc > 1 && fixed + (size_t)Tc * 1572864 > ws_size) Tc >>= 1;

  hipMemsetAsync(hP0, 0, 262144, stream);
  hipMemsetAsync(hF0, 0, 524288, stream);
  pack_w_kernel<<<768, 256, 0, stream>>>(Wi, WiP, 16);
  pack_w_kernel<<<1536, 256, 0, stream>>>(Wh, WhP, 32);

  _Float16* hP[2] = {hP0, hP1};
  float*    hF[2] = {hF0, hF1};

  const int nChunks = Tdim / Tc;
  for (int c = 0; c < nChunks; ++c) {
    gemm_xi_kernel<<<dim3(Tc * 2, 24), 256, 0, stream>>>(x, WiP, bi, xiC, c * Tc);
    for (int tl = 0; tl < Tc; ++tl) {
      const int t = c * Tc + tl;
      float* dstF = (t == Tdim - 1) ? out : hF[(t + 1) & 1];
      gru_step_kernel<<<dim3(64, 2), 256, 0, stream>>>(WhP, hP[t & 1], hF[t & 1], xiC, bh,
                                                       dstF, hP[(t + 1) & 1], tl);
    }
  }
}

// Round 6
// 8379.459 us; speedup vs baseline: 1.0157x; 1.0157x over previous
//
#include <hip/hip_runtime.h>
#include <hip/hip_cooperative_groups.h>
#include <cstdint>
#include <cstddef>

namespace cg = cooperative_groups;

typedef _Float16 f16x8 __attribute__((ext_vector_type(8)));
typedef float f32x4 __attribute__((ext_vector_type(4)));

#define Bdim 128
#define Tdim 512
#define Ddim 512
#define Hdim 1024
#define H3 3072

// ---------------------------------------------------------------------------
// Pack fp32 weight matrix W[K][3072] into fp16 MFMA B-fragment tiles:
// P[((nt*KT + kt)*64 + lane)*8 + i] = W[(kt*32 + (lane>>4)*8 + i)*3072 + nt*16 + (lane&15)]
// ---------------------------------------------------------------------------
__global__ __launch_bounds__(256) void pack_w_kernel(const float* __restrict__ W,
                                                     _Float16* __restrict__ P, int KT) {
  int u = blockIdx.x * 256 + threadIdx.x;
  int lane = u & 63;
  int kt = (u >> 6) & (KT - 1);
  int nt = (u >> 6) / KT;
  int n = (nt << 4) + (lane & 15);
  int k0 = (kt << 5) + ((lane >> 4) << 3);
  const float* src = W + (size_t)k0 * H3 + n;
  f16x8 v;
#pragma unroll
  for (int i = 0; i < 8; ++i) v[i] = (_Float16)src[(size_t)i * H3];
  *(f16x8*)(P + (size_t)u * 8) = v;
}

// ---------------------------------------------------------------------------
// xi chunk GEMM: xi[tl][b][n] = x[b][tbase+tl][:] @ Wi[:, n] + bi[n]  (fp16 out)
// ---------------------------------------------------------------------------
__global__ __launch_bounds__(256) void gemm_xi_kernel(const float* __restrict__ x,
                                                      const _Float16* __restrict__ WiP,
                                                      const float* __restrict__ bi,
                                                      _Float16* __restrict__ xi, int tbase) {
  const int w = threadIdx.x >> 6, lane = threadIdx.x & 63;
  const int wm = w >> 1, wn = w & 1;
  const int bx = blockIdx.x, by = blockIdx.y;
  const int rbase = bx * 64 + wm * 32;

  f32x4 acc[2][4] = {};

  const int kA = (lane >> 4) << 3;
  const float* xrow[2];
#pragma unroll
  for (int mt2 = 0; mt2 < 2; ++mt2) {
    int row = rbase + mt2 * 16 + (lane & 15);
    int b = row & (Bdim - 1), tl = row >> 7;
    xrow[mt2] = x + ((size_t)b * Tdim + (tbase + tl)) * Ddim + kA;
  }
  const int nt0 = by * 8 + wn * 4;

  for (int kt = 0; kt < 16; ++kt) {
    f16x8 a[2];
#pragma unroll
    for (int mt2 = 0; mt2 < 2; ++mt2) {
      const float* p = xrow[mt2] + kt * 32;
      float4 lo = *(const float4*)p;
      float4 hi = *(const float4*)(p + 4);
      f16x8 v;
      v[0] = (_Float16)lo.x; v[1] = (_Float16)lo.y; v[2] = (_Float16)lo.z; v[3] = (_Float16)lo.w;
      v[4] = (_Float16)hi.x; v[5] = (_Float16)hi.y; v[6] = (_Float16)hi.z; v[7] = (_Float16)hi.w;
      a[mt2] = v;
    }
#pragma unroll
    for (int nt4 = 0; nt4 < 4; ++nt4) {
      const int nt = nt0 + nt4;
      f16x8 bf = *(const f16x8*)(WiP + (((size_t)nt * 16 + kt) * 64 + lane) * 8);
#pragma unroll
      for (int mt2 = 0; mt2 < 2; ++mt2)
        acc[mt2][nt4] = __builtin_amdgcn_mfma_f32_16x16x32_f16(a[mt2], bf, acc[mt2][nt4], 0, 0, 0);
    }
  }

#pragma unroll
  for (int mt2 = 0; mt2 < 2; ++mt2) {
    const int rowb = rbase + mt2 * 16 + ((lane >> 4) << 2);
#pragma unroll
    for (int nt4 = 0; nt4 < 4; ++nt4) {
      const int n = ((nt0 + nt4) << 4) + (lane & 15);
      const float biv = bi[n];
#pragma unroll
      for (int reg = 0; reg < 4; ++reg) {
        const int row = rowb + reg;
        const int b = row & (Bdim - 1), tl = row >> 7;
        xi[((size_t)tl * Bdim + b) * H3 + n] = (_Float16)(acc[mt2][nt4][reg] + biv);
      }
    }
  }
}

// ---------------------------------------------------------------------------
// Persistent GRU recurrence (cooperative).  grid 256 x 256 threads (4 waves).
// ---------------------------------------------------------------------------
__global__ __launch_bounds__(256, 1) void gru_persist(
    const _Float16* __restrict__ WhP,
    _Float16* __restrict__ hP0, _Float16* __restrict__ hP1,
    float* __restrict__ hF,
    const _Float16* __restrict__ xiC,
    const float* __restrict__ bh,
    float* __restrict__ out,
    int tbase, int Tc) {
  cg::grid_group grid = cg::this_grid();

  const int w = threadIdx.x >> 6, lane = threadIdx.x & 63;
  const int ub = w >> 1, kw = w & 1;
  const int u = blockIdx.x * 2 + ub;
  const int mt = u & 7, js = u >> 3;
  const int j = (js << 4) + (lane & 15);
  const int rowg = lane >> 4;

  f16x8 bfr[3][16];
#pragma unroll
  for (int g = 0; g < 3; ++g)
#pragma unroll
    for (int kk = 0; kk < 16; ++kk)
      bfr[g][kk] = *(const f16x8*)(WhP +
          ((((size_t)(g * 64 + js)) * 32 + (kw * 16 + kk)) * 64 + lane) * 8);

  const float bh_r = bh[j], bh_z = bh[Hdim + j], bh_n = bh[2 * Hdim + j];

  const int rl0 = (rowg << 2) + 2 * kw;
  const int b0 = (mt << 4) + rl0;
  float hp0 = hF[(size_t)b0 * Hdim + j];
  float hp1 = hF[(size_t)(b0 + 1) * Hdim + j];

  const int laneP0 = rl0 + (((j >> 3) & 3) << 4);
  const int ip = j & 7;
  const size_t pbase = (((size_t)(j >> 5) * 8 + mt) * 64) * 8 + ip;

  __shared__ f32x4 part[4][3][64];

  for (int tl = 0; tl < Tc; ++tl) {
    const int t = tbase + tl;
    const _Float16* hPs = (t & 1) ? hP1 : hP0;
    _Float16* hPd = (t & 1) ? hP0 : hP1;

    f32x4 acc[3] = {};
#pragma unroll
    for (int kk = 0; kk < 16; ++kk) {
      f16x8 a = *(const f16x8*)(hPs +
          ((((size_t)(kw * 16 + kk)) * 8 + mt) * 64 + lane) * 8);
      acc[0] = __builtin_amdgcn_mfma_f32_16x16x32_f16(a, bfr[0][kk], acc[0], 0, 0, 0);
      acc[1] = __builtin_amdgcn_mfma_f32_16x16x32_f16(a, bfr[1][kk], acc[1], 0, 0, 0);
      acc[2] = __builtin_amdgcn_mfma_f32_16x16x32_f16(a, bfr[2][kk], acc[2], 0, 0, 0);
    }

    part[w][0][lane] = acc[0];
    part[w][1][lane] = acc[1];
    part[w][2][lane] = acc[2];
    __syncthreads();

    const int pw = w ^ 1;
    float s0[3], s1[3];
    if (kw == 0) {
#pragma unroll
      for (int g = 0; g < 3; ++g) {
        f32x4 p = part[pw][g][lane];
        s0[g] = acc[g][0] + p[0];
        s1[g] = acc[g][1] + p[1];
      }
    } else {
#pragma unroll
      for (int g = 0; g < 3; ++g) {
        f32x4 p = part[pw][g][lane];
        s0[g] = acc[g][2] + p[2];
        s1[g] = acc[g][3] + p[3];
      }
    }

    const _Float16* xr = xiC + ((size_t)tl * Bdim + b0) * H3 + j;
    const float xir0 = (float)xr[0], xiz0 = (float)xr[Hdim], xin0 = (float)xr[2 * Hdim];
    const float xir1 = (float)xr[H3], xiz1 = (float)xr[H3 + Hdim], xin1 = (float)xr[H3 + 2 * Hdim];

    const float r0g = 1.f / (1.f + __expf(-(xir0 + s0[0] + bh_r)));
    const float z0g = 1.f / (1.f + __expf(-(xiz0 + s0[1] + bh_z)));
    const float n0a = xin0 + r0g * (s0[2] + bh_n);
    const float n0g = 2.f / (1.f + __expf(-2.f * n0a)) - 1.f;
    const float hy0 = z0g * n0g + (1.f - z0g) * hp0;

    const float r1g = 1.f / (1.f + __expf(-(xir1 + s1[0] + bh_r)));
    const float z1g = 1.f / (1.f + __expf(-(xiz1 + s1[1] + bh_z)));
    const float n1a = xin1 + r1g * (s1[2] + bh_n);
    const float n1g = 2.f / (1.f + __expf(-2.f * n1a)) - 1.f;
    const float hy1 = z1g * n1g + (1.f - z1g) * hp1;

    hp0 = hy0;
    hp1 = hy1;

    hPd[pbase + (size_t)laneP0 * 8] = (_Float16)hy0;
    hPd[pbase + (size_t)(laneP0 + 1) * 8] = (_Float16)hy1;

    if (tl == Tc - 1) {
      hF[(size_t)b0 * Hdim + j] = hy0;
      hF[(size_t)(b0 + 1) * Hdim + j] = hy1;
    }
    if (t == Tdim - 1) {
      out[(size_t)b0 * Hdim + j] = hy0;
      out[(size_t)(b0 + 1) * Hdim + j] = hy1;
    }

    grid.sync();
  }
}

// ---------------------------------------------------------------------------
// Fallback: one GRU timestep per launch (Round-1 proven kernel, fp16 xi).
// grid (64, 2), block 256 (4 waves).
// ---------------------------------------------------------------------------
__global__ __launch_bounds__(256) void gru_step_kernel(
    const _Float16* __restrict__ WhP, const _Float16* __restrict__ hPs,
    const float* __restrict__ hFs, const _Float16* __restrict__ xi,
    const float* __restrict__ bh,
    float* __restrict__ hFd, _Float16* __restrict__ hPd, int tl) {
  const int wg = blockIdx.x;
  const int wgm = blockIdx.y;
  const int w = threadIdx.x >> 6;
  const int lane = threadIdx.x & 63;
  const int mtg = wgm * 4 + w;
  const int j0 = wg << 4;

  f32x4 acc[3] = {};

  const _Float16* aP = hPs + ((size_t)mtg * 64 + lane) * 8;
  const _Float16* bP0 = WhP + (((size_t)(0 * 64 + wg) * 32) * 64 + lane) * 8;
  const _Float16* bP1 = WhP + (((size_t)(1 * 64 + wg) * 32) * 64 + lane) * 8;
  const _Float16* bP2 = WhP + (((size_t)(2 * 64 + wg) * 32) * 64 + lane) * 8;

#pragma unroll 4
  for (int kt = 0; kt < 32; ++kt) {
    f16x8 a = *(const f16x8*)(aP + (size_t)kt * (8 * 64 * 8));
    f16x8 b0 = *(const f16x8*)(bP0 + (size_t)kt * (64 * 8));
    f16x8 b1 = *(const f16x8*)(bP1 + (size_t)kt * (64 * 8));
    f16x8 b2 = *(const f16x8*)(bP2 + (size_t)kt * (64 * 8));
    acc[0] = __builtin_amdgcn_mfma_f32_16x16x32_f16(a, b0, acc[0], 0, 0, 0);
    acc[1] = __builtin_amdgcn_mfma_f32_16x16x32_f16(a, b1, acc[1], 0, 0, 0);
    acc[2] = __builtin_amdgcn_mfma_f32_16x16x32_f16(a, b2, acc[2], 0, 0, 0);
  }

  const int j = j0 + (lane & 15);
  const float bhr = bh[j], bhz = bh[Hdim + j], bhn = bh[2 * Hdim + j];
  const int lanehi = ((wg & 1) << 1) + ((lane & 15) >> 3);
  const int ip = lane & 7;
  const int ktp = wg >> 1;
  const int rbase = (mtg << 4) + ((lane >> 4) << 2);

#pragma unroll
  for (int reg = 0; reg < 4; ++reg) {
    const int b = rbase + reg;
    const _Float16* xr = xi + ((size_t)tl * Bdim + b) * H3 + j;
    const float xirv = (float)xr[0], xizv = (float)xr[Hdim], xinv = (float)xr[2 * Hdim];
    const float whr = acc[0][reg] + bhr;
    const float whz = acc[1][reg] + bhz;
    const float whn = acc[2][reg] + bhn;
    const float hprev = hFs[(size_t)b * Hdim + j];
    const float r = 1.f / (1.f + __expf(-(xirv + whr)));
    const float z = 1.f / (1.f + __expf(-(xizv + whz)));
    const float nn = tanhf(xinv + r * whn);
    const float hy = z * nn + (1.f - z) * hprev;
    hFd[(size_t)b * Hdim + j] = hy;
    const int laneP = (b & 15) + (lanehi << 4);
    hPd[(((size_t)ktp * 8 + mtg) * 64 + laneP) * 8 + ip] = (_Float16)hy;
  }
}

// ---------------------------------------------------------------------------
extern "C" void kernel_launch(void* const* d_in, const int* in_sizes, int n_in,
                              void* d_out, int out_size, void* d_ws, size_t ws_size,
                              hipStream_t stream) {
  const float* x  = (const float*)d_in[0];
  const float* Wi = (const float*)d_in[1];
  const float* bi = (const float*)d_in[2];
  const float* Wh = (const float*)d_in[3];
  const float* bh = (const float*)d_in[4];
  float* out = (float*)d_out;
  char* ws = (char*)d_ws;

  // workspace layout (bytes)
  _Float16* WiP = (_Float16*)(ws + 0);          // 3,145,728
  _Float16* WhP = (_Float16*)(ws + 3145728);    // 6,291,456
  _Float16* hP0 = (_Float16*)(ws + 9437184);    //   262,144
  _Float16* hP1 = (_Float16*)(ws + 9699328);    //   262,144
  float*    hF0 = (float*)(ws + 9961472);       //   524,288
  float*    hF1 = (float*)(ws + 10485760);      //   524,288
  _Float16* xiC = (_Float16*)(ws + 11010048);   // Tc * 786,432 (fp16)
  const size_t fixed = 11010048;

  int Tc = 512;
  while (Tc > 1 && fixed + (size_t)Tc * 786432 > ws_size) Tc >>= 1;

  hipMemsetAsync(hP0, 0, 262144, stream);
  hipMemsetAsync(hF0, 0, 524288, stream);
  pack_w_kernel<<<768, 256, 0, stream>>>(Wi, WiP, 16);
  pack_w_kernel<<<1536, 256, 0, stream>>>(Wh, WhP, 32);

  _Float16* hP[2] = {hP0, hP1};
  float*    hF[2] = {hF0, hF1};

  // Decide cooperative viability from the runtime's own occupancy math
  // (host-only queries; graph-capture-safe; recomputed every call).
  int useCoop = 0;
  {
    int dev = 0;
    (void)hipGetDevice(&dev);
    int coopAttr = 0;
    (void)hipDeviceGetAttribute(&coopAttr, hipDeviceAttributeCooperativeLaunch, dev);
    if (coopAttr) {
      int mbPerCU = 0;
      if (hipOccupancyMaxActiveBlocksPerMultiprocessor(&mbPerCU, (const void*)gru_persist,
                                                       256, 0) == hipSuccess) {
        int ncu = 0;
        (void)hipDeviceGetAttribute(&ncu, hipDeviceAttributeMultiprocessorCount, dev);
        if ((long)mbPerCU * (long)ncu >= 256) useCoop = 1;
      }
    }
    if (Tc < 2) useCoop = 0;  // parity compatibility with fallback
  }

  const int nChunks = Tdim / Tc;
  for (int c = 0; c < nChunks; ++c) {
    int tbase = c * Tc;
    gemm_xi_kernel<<<dim3(Tc * 2, 24), 256, 0, stream>>>(x, WiP, bi, xiC, tbase);

    bool done = false;
    if (useCoop) {
      float* hFc = hF0;
      void* args[] = {(void*)&WhP, (void*)&hP0, (void*)&hP1, (void*)&hFc,
                      (void*)&xiC, (void*)&bh, (void*)&out, (void*)&tbase, (void*)&Tc};
      hipError_t e = hipLaunchCooperativeKernel((void*)gru_persist, dim3(256), dim3(256),
                                                args, 0, stream);
      if (e == hipSuccess) {
        done = true;
      } else {
        (void)hipGetLastError();  // clear sticky error
        useCoop = 0;
      }
    }
    if (!done) {
      for (int tl = 0; tl < Tc; ++tl) {
        const int t = tbase + tl;
        float* dstF = (t == Tdim - 1) ? out : hF[(t + 1) & 1];
        gru_step_kernel<<<dim3(64, 2), 256, 0, stream>>>(WhP, hP[t & 1], hF[t & 1], xiC, bh,
                                                         dstF, hP[(t + 1) & 1], tl);
      }
    }
  }
}

// Round 7
// 5503.665 us; speedup vs baseline: 1.5464x; 1.5225x over previous
//
#include <hip/hip_runtime.h>
#include <cstdint>
#include <cstddef>

typedef _Float16 f16x8 __attribute__((ext_vector_type(8)));
typedef float f32x4 __attribute__((ext_vector_type(4)));
typedef unsigned long long ull;

#define Bdim 128
#define Tdim 512
#define Ddim 512
#define Hdim 1024
#define H3 3072

#define MFMA16(a, b, c) __builtin_amdgcn_mfma_f32_16x16x32_f16((a), (b), (c), 0, 0, 0)

// ---------------------------------------------------------------------------
// Pack fp32 weight matrix W[K][3072] into fp16 MFMA B-fragment tiles:
// P[((nt*KT + kt)*64 + lane)*8 + i] = W[(kt*32 + (lane>>4)*8 + i)*3072 + nt*16 + (lane&15)]
// ---------------------------------------------------------------------------
__global__ __launch_bounds__(256) void pack_w_kernel(const float* __restrict__ W,
                                                     _Float16* __restrict__ P, int KT) {
  int u = blockIdx.x * 256 + threadIdx.x;
  int lane = u & 63;
  int kt = (u >> 6) & (KT - 1);
  int nt = (u >> 6) / KT;
  int n = (nt << 4) + (lane & 15);
  int k0 = (kt << 5) + ((lane >> 4) << 3);
  const float* src = W + (size_t)k0 * H3 + n;
  f16x8 v;
#pragma unroll
  for (int i = 0; i < 8; ++i) v[i] = (_Float16)src[(size_t)i * H3];
  *(f16x8*)(P + (size_t)u * 8) = v;
}

// ---------------------------------------------------------------------------
// Fused persistent GRU: xi GEMM + recurrence in ONE kernel, 256 blocks x 256.
// block = (js strip of 16 h-cols, mt-pair); unit = (mt, js), wave pair splits K.
// B-fragments (Wh 96KB + Wi 48KB) in LDS.  h exchanged via agent-scope atomics
// (bypass L2 -> no cache flushes needed).  Hand-rolled arrival/release barrier.
// ---------------------------------------------------------------------------
__global__ __launch_bounds__(256, 1) void gru_fused(
    const float* __restrict__ x,
    const _Float16* __restrict__ WiP,
    const _Float16* __restrict__ WhP,
    const float* __restrict__ bi,
    const float* __restrict__ bh,
    _Float16* __restrict__ hP0, _Float16* __restrict__ hP1,
    unsigned int* __restrict__ rel,    // [512]
    unsigned int* __restrict__ done,   // [512][256]
    float* __restrict__ out) {
  extern __shared__ char smem[];
  _Float16* sWh = (_Float16*)smem;                  // [3][32][64][8]  96 KB
  _Float16* sWi = (_Float16*)(smem + 98304);        // [3][16][64][8]  48 KB
  float2* part = (float2*)(smem + 98304 + 49152);   // [4][6][64]      12 KB

  const int tid = threadIdx.x;
  const int w = tid >> 6, lane = tid & 63;
  const int ub = w >> 1, kw = w & 1;
  const int bid = blockIdx.x;
  const int js = bid >> 2;
  const int mtp = bid & 3;
  const int mt = mtp * 2 + ub;
  const int j = (js << 4) + (lane & 15);
  const int rowg = lane >> 4;

  // ---- one-time LDS fill of B fragments for this js strip ----
  {
    const f16x8* srcWh = (const f16x8*)WhP;
    f16x8* dWh = (f16x8*)sWh;
#pragma unroll
    for (int g = 0; g < 3; ++g) {
      const size_t sb = (size_t)(g * 64 + js) * 2048;
      for (int i2 = tid; i2 < 2048; i2 += 256) dWh[g * 2048 + i2] = srcWh[sb + i2];
    }
    const f16x8* srcWi = (const f16x8*)WiP;
    f16x8* dWi = (f16x8*)sWi;
#pragma unroll
    for (int g = 0; g < 3; ++g) {
      const size_t sb = (size_t)(g * 64 + js) * 1024;
      for (int i2 = tid; i2 < 1024; i2 += 256) dWi[g * 1024 + i2] = srcWi[sb + i2];
    }
  }
  __syncthreads();

  const float bh_r = bh[j], bh_z = bh[Hdim + j], bh_n = bh[2 * Hdim + j];
  const float bi_r = bi[j], bi_z = bi[Hdim + j], bi_n = bi[2 * Hdim + j];

  const int rl0 = (rowg << 2) + 2 * kw;   // first of this thread's 2 rows in tile
  const int b0 = (mt << 4) + rl0;

  float hp0 = 0.f, hp1 = 0.f;             // running h in fp32 registers

  // x addressing: row b = mt*16 + (lane&15), element k = kt*32 + (lane>>4)*8 + i
  const float* xbase = x + (size_t)(mt * 16 + (lane & 15)) * Tdim * Ddim + ((lane >> 4) << 3);

  // packed-h dword store index (uint32 units), cols (jcol, jcol+1), row rowSt
  const int jm = (lane & 15) & ~1;
  const int jcol = (js << 4) + jm;
  const int rowSt15 = rl0 + (lane & 1);
  const unsigned stIdx = (unsigned)(((jcol >> 5) * 4096 + mt * 512 + rowSt15 * 8 +
                                     ((jcol >> 3) & 3) * 128 + (jcol & 7)) >> 1);

  f32x4 xacc0, xacc1, xacc2;
#define WI_GEMM(tt)                                                             \
  {                                                                             \
    xacc0 = (f32x4){0.f, 0.f, 0.f, 0.f};                                        \
    xacc1 = xacc0; xacc2 = xacc0;                                               \
    _Pragma("unroll")                                                           \
    for (int kk = 0; kk < 8; ++kk) {                                            \
      const int kt = kw * 8 + kk;                                               \
      const float* xp = xbase + (size_t)(tt) * Ddim + kt * 32;                  \
      float4 lo = *(const float4*)xp;                                           \
      float4 hi = *(const float4*)(xp + 4);                                     \
      f16x8 a;                                                                  \
      a[0] = (_Float16)lo.x; a[1] = (_Float16)lo.y;                             \
      a[2] = (_Float16)lo.z; a[3] = (_Float16)lo.w;                             \
      a[4] = (_Float16)hi.x; a[5] = (_Float16)hi.y;                             \
      a[6] = (_Float16)hi.z; a[7] = (_Float16)hi.w;                             \
      f16x8 B0 = *(const f16x8*)(sWi + (size_t)((0 * 16 + kt) * 64 + lane) * 8);\
      f16x8 B1 = *(const f16x8*)(sWi + (size_t)((1 * 16 + kt) * 64 + lane) * 8);\
      f16x8 B2 = *(const f16x8*)(sWi + (size_t)((2 * 16 + kt) * 64 + lane) * 8);\
      xacc0 = MFMA16(a, B0, xacc0);                                             \
      xacc1 = MFMA16(a, B1, xacc1);                                             \
      xacc2 = MFMA16(a, B2, xacc2);                                             \
    }                                                                           \
  }

  WI_GEMM(0);

  for (int t = 0; t < Tdim; ++t) {
    const _Float16* hPs = (t & 1) ? hP1 : hP0;
    _Float16* hPd = (t & 1) ? hP0 : hP1;

    // ---- Wh GEMM: A (packed h) via agent-scope coherent loads, B from LDS ----
    f32x4 wacc0 = (f32x4){0.f, 0.f, 0.f, 0.f}, wacc1 = wacc0, wacc2 = wacc0;
#pragma unroll
    for (int kk = 0; kk < 16; ++kk) {
      const int kt = kw * 16 + kk;
      ull* ap = (ull*)(hPs + (size_t)((kt * 8 + mt) * 64 + lane) * 8);
      ull u0 = __hip_atomic_load(ap, __ATOMIC_RELAXED, __HIP_MEMORY_SCOPE_AGENT);
      ull u1 = __hip_atomic_load(ap + 1, __ATOMIC_RELAXED, __HIP_MEMORY_SCOPE_AGENT);
      union { ull u[2]; f16x8 v; } cv;
      cv.u[0] = u0; cv.u[1] = u1;
      f16x8 a = cv.v;
      f16x8 B0 = *(const f16x8*)(sWh + (size_t)((0 * 32 + kt) * 64 + lane) * 8);
      f16x8 B1 = *(const f16x8*)(sWh + (size_t)((1 * 32 + kt) * 64 + lane) * 8);
      f16x8 B2 = *(const f16x8*)(sWh + (size_t)((2 * 32 + kt) * 64 + lane) * 8);
      wacc0 = MFMA16(a, B0, wacc0);
      wacc1 = MFMA16(a, B1, wacc1);
      wacc2 = MFMA16(a, B2, wacc2);
    }

    // ---- cross-wave K reduction (publish the 2 regs the partner finalizes) ----
    float2* myp = part + (size_t)(w * 6) * 64 + lane;
    myp[0 * 64] = kw ? make_float2(wacc0[0], wacc0[1]) : make_float2(wacc0[2], wacc0[3]);
    myp[1 * 64] = kw ? make_float2(wacc1[0], wacc1[1]) : make_float2(wacc1[2], wacc1[3]);
    myp[2 * 64] = kw ? make_float2(wacc2[0], wacc2[1]) : make_float2(wacc2[2], wacc2[3]);
    myp[3 * 64] = kw ? make_float2(xacc0[0], xacc0[1]) : make_float2(xacc0[2], xacc0[3]);
    myp[4 * 64] = kw ? make_float2(xacc1[0], xacc1[1]) : make_float2(xacc1[2], xacc1[3]);
    myp[5 * 64] = kw ? make_float2(xacc2[0], xacc2[1]) : make_float2(xacc2[2], xacc2[3]);
    __syncthreads();
    const float2* pp = part + (size_t)((w ^ 1) * 6) * 64 + lane;
    const float2 pw0 = pp[0 * 64], pw1 = pp[1 * 64], pw2 = pp[2 * 64];
    const float2 px0 = pp[3 * 64], px1 = pp[4 * 64], px2 = pp[5 * 64];

    const float whr0 = (kw ? wacc0[2] : wacc0[0]) + pw0.x, whr1 = (kw ? wacc0[3] : wacc0[1]) + pw0.y;
    const float whz0 = (kw ? wacc1[2] : wacc1[0]) + pw1.x, whz1 = (kw ? wacc1[3] : wacc1[1]) + pw1.y;
    const float whn0 = (kw ? wacc2[2] : wacc2[0]) + pw2.x, whn1 = (kw ? wacc2[3] : wacc2[1]) + pw2.y;
    const float xir0 = (kw ? xacc0[2] : xacc0[0]) + px0.x + bi_r, xir1 = (kw ? xacc0[3] : xacc0[1]) + px0.y + bi_r;
    const float xiz0 = (kw ? xacc1[2] : xacc1[0]) + px1.x + bi_z, xiz1 = (kw ? xacc1[3] : xacc1[1]) + px1.y + bi_z;
    const float xin0 = (kw ? xacc2[2] : xacc2[0]) + px2.x + bi_n, xin1 = (kw ? xacc2[3] : xacc2[1]) + px2.y + bi_n;

    // ---- gates ----
    const float r0 = 1.f / (1.f + __expf(-(xir0 + whr0 + bh_r)));
    const float z0 = 1.f / (1.f + __expf(-(xiz0 + whz0 + bh_z)));
    const float na0 = xin0 + r0 * (whn0 + bh_n);
    const float n0 = 2.f / (1.f + __expf(-2.f * na0)) - 1.f;
    const float hy0 = z0 * n0 + (1.f - z0) * hp0;
    const float r1 = 1.f / (1.f + __expf(-(xir1 + whr1 + bh_r)));
    const float z1 = 1.f / (1.f + __expf(-(xiz1 + whz1 + bh_z)));
    const float na1 = xin1 + r1 * (whn1 + bh_n);
    const float n1 = 2.f / (1.f + __expf(-2.f * na1)) - 1.f;
    const float hy1 = z1 * n1 + (1.f - z1) * hp1;
    hp0 = hy0;
    hp1 = hy1;

    // ---- packed-h store: pair adjacent cols via shfl, one dword per thread ----
    const float h0p = __shfl_xor(hy0, 1);
    const float h1p = __shfl_xor(hy1, 1);
    const int odd = lane & 1;
    union { _Float16 h[2]; unsigned int u; } pk;
    pk.h[0] = (_Float16)(odd ? h1p : hy0);
    pk.h[1] = (_Float16)(odd ? hy1 : h0p);
    __hip_atomic_store((unsigned int*)hPd + stIdx, pk.u, __ATOMIC_RELAXED,
                       __HIP_MEMORY_SCOPE_AGENT);

    if (t == Tdim - 1) {
      out[(size_t)b0 * Hdim + j] = hy0;
      out[(size_t)(b0 + 1) * Hdim + j] = hy1;
      break;
    }

    // ---- barrier: arrive, overlap next-step Wi GEMM, wait release ----
    asm volatile("s_waitcnt vmcnt(0)" ::: "memory");
    __syncthreads();
    if (tid == 0)
      __hip_atomic_store(&done[t * 256 + bid], 1u, __ATOMIC_RELAXED, __HIP_MEMORY_SCOPE_AGENT);

    WI_GEMM(t + 1);

    if (bid == 0) {
      while (__hip_atomic_load(&done[t * 256 + tid], __ATOMIC_RELAXED,
                               __HIP_MEMORY_SCOPE_AGENT) == 0u)
        __builtin_amdgcn_s_sleep(1);
      __syncthreads();
      if (tid == 0)
        __hip_atomic_store(&rel[t], 1u, __ATOMIC_RELAXED, __HIP_MEMORY_SCOPE_AGENT);
    } else {
      if (tid == 0) {
        while (__hip_atomic_load(&rel[t], __ATOMIC_RELAXED, __HIP_MEMORY_SCOPE_AGENT) == 0u)
          __builtin_amdgcn_s_sleep(1);
      }
    }
    __syncthreads();
  }
}

// ---------------------------------------------------------------------------
// Fallback path (ncu != 256 or fused launch refused): chunked xi GEMM +
// per-step kernels (proven Round-1 machinery, fp16 xi).
// ---------------------------------------------------------------------------
__global__ __launch_bounds__(256) void gemm_xi_kernel(const float* __restrict__ x,
                                                      const _Float16* __restrict__ WiP,
                                                      const float* __restrict__ bi,
                                                      _Float16* __restrict__ xi, int tbase) {
  const int w = threadIdx.x >> 6, lane = threadIdx.x & 63;
  const int wm = w >> 1, wn = w & 1;
  const int bx = blockIdx.x, by = blockIdx.y;
  const int rbase = bx * 64 + wm * 32;

  f32x4 acc[2][4] = {};

  const int kA = (lane >> 4) << 3;
  const float* xrow[2];
#pragma unroll
  for (int mt2 = 0; mt2 < 2; ++mt2) {
    int row = rbase + mt2 * 16 + (lane & 15);
    int b = row & (Bdim - 1), tl = row >> 7;
    xrow[mt2] = x + ((size_t)b * Tdim + (tbase + tl)) * Ddim + kA;
  }
  const int nt0 = by * 8 + wn * 4;

  for (int kt = 0; kt < 16; ++kt) {
    f16x8 a[2];
#pragma unroll
    for (int mt2 = 0; mt2 < 2; ++mt2) {
      const float* p = xrow[mt2] + kt * 32;
      float4 lo = *(const float4*)p;
      float4 hi = *(const float4*)(p + 4);
      f16x8 v;
      v[0] = (_Float16)lo.x; v[1] = (_Float16)lo.y; v[2] = (_Float16)lo.z; v[3] = (_Float16)lo.w;
      v[4] = (_Float16)hi.x; v[5] = (_Float16)hi.y; v[6] = (_Float16)hi.z; v[7] = (_Float16)hi.w;
      a[mt2] = v;
    }
#pragma unroll
    for (int nt4 = 0; nt4 < 4; ++nt4) {
      const int nt = nt0 + nt4;
      f16x8 bf = *(const f16x8*)(WiP + (((size_t)nt * 16 + kt) * 64 + lane) * 8);
#pragma unroll
      for (int mt2 = 0; mt2 < 2; ++mt2)
        acc[mt2][nt4] = MFMA16(a[mt2], bf, acc[mt2][nt4]);
    }
  }

#pragma unroll
  for (int mt2 = 0; mt2 < 2; ++mt2) {
    const int rowb = rbase + mt2 * 16 + ((lane >> 4) << 2);
#pragma unroll
    for (int nt4 = 0; nt4 < 4; ++nt4) {
      const int n = ((nt0 + nt4) << 4) + (lane & 15);
      const float biv = bi[n];
#pragma unroll
      for (int reg = 0; reg < 4; ++reg) {
        const int row = rowb + reg;
        const int b = row & (Bdim - 1), tl = row >> 7;
        xi[((size_t)tl * Bdim + b) * H3 + n] = (_Float16)(acc[mt2][nt4][reg] + biv);
      }
    }
  }
}

__global__ __launch_bounds__(256) void gru_step_kernel(
    const _Float16* __restrict__ WhP, const _Float16* __restrict__ hPs,
    const float* __restrict__ hFs, const _Float16* __restrict__ xi,
    const float* __restrict__ bh,
    float* __restrict__ hFd, _Float16* __restrict__ hPd, int tl) {
  const int wg = blockIdx.x;
  const int wgm = blockIdx.y;
  const int w = threadIdx.x >> 6;
  const int lane = threadIdx.x & 63;
  const int mtg = wgm * 4 + w;
  const int j0 = wg << 4;

  f32x4 acc[3] = {};

  const _Float16* aP = hPs + ((size_t)mtg * 64 + lane) * 8;
  const _Float16* bP0 = WhP + (((size_t)(0 * 64 + wg) * 32) * 64 + lane) * 8;
  const _Float16* bP1 = WhP + (((size_t)(1 * 64 + wg) * 32) * 64 + lane) * 8;
  const _Float16* bP2 = WhP + (((size_t)(2 * 64 + wg) * 32) * 64 + lane) * 8;

#pragma unroll 4
  for (int kt = 0; kt < 32; ++kt) {
    f16x8 a = *(const f16x8*)(aP + (size_t)kt * (8 * 64 * 8));
    f16x8 b0 = *(const f16x8*)(bP0 + (size_t)kt * (64 * 8));
    f16x8 b1 = *(const f16x8*)(bP1 + (size_t)kt * (64 * 8));
    f16x8 b2 = *(const f16x8*)(bP2 + (size_t)kt * (64 * 8));
    acc[0] = MFMA16(a, b0, acc[0]);
    acc[1] = MFMA16(a, b1, acc[1]);
    acc[2] = MFMA16(a, b2, acc[2]);
  }

  const int j = j0 + (lane & 15);
  const float bhr = bh[j], bhz = bh[Hdim + j], bhn = bh[2 * Hdim + j];
  const int lanehi = ((wg & 1) << 1) + ((lane & 15) >> 3);
  const int ip = lane & 7;
  const int ktp = wg >> 1;
  const int rbase = (mtg << 4) + ((lane >> 4) << 2);

#pragma unroll
  for (int reg = 0; reg < 4; ++reg) {
    const int b = rbase + reg;
    const _Float16* xr = xi + ((size_t)tl * Bdim + b) * H3 + j;
    const float xirv = (float)xr[0], xizv = (float)xr[Hdim], xinv = (float)xr[2 * Hdim];
    const float whr = acc[0][reg] + bhr;
    const float whz = acc[1][reg] + bhz;
    const float whn = acc[2][reg] + bhn;
    const float hprev = hFs[(size_t)b * Hdim + j];
    const float r = 1.f / (1.f + __expf(-(xirv + whr)));
    const float z = 1.f / (1.f + __expf(-(xizv + whz)));
    const float nn = tanhf(xinv + r * whn);
    const float hy = z * nn + (1.f - z) * hprev;
    hFd[(size_t)b * Hdim + j] = hy;
    const int laneP = (b & 15) + (lanehi << 4);
    hPd[(((size_t)ktp * 8 + mtg) * 64 + laneP) * 8 + ip] = (_Float16)hy;
  }
}

// ---------------------------------------------------------------------------
extern "C" void kernel_launch(void* const* d_in, const int* in_sizes, int n_in,
                              void* d_out, int out_size, void* d_ws, size_t ws_size,
                              hipStream_t stream) {
  const float* x  = (const float*)d_in[0];
  const float* Wi = (const float*)d_in[1];
  const float* bi = (const float*)d_in[2];
  const float* Wh = (const float*)d_in[3];
  const float* bh = (const float*)d_in[4];
  float* out = (float*)d_out;
  char* ws = (char*)d_ws;

  // workspace layout (bytes)
  _Float16* WiP = (_Float16*)(ws + 0);           //  3,145,728
  _Float16* WhP = (_Float16*)(ws + 3145728);     //  6,291,456
  _Float16* hP0 = (_Float16*)(ws + 9437184);     //    262,144
  _Float16* hP1 = (_Float16*)(ws + 9699328);     //    262,144
  unsigned int* rel  = (unsigned int*)(ws + 9961472);  //   2,048
  unsigned int* done = (unsigned int*)(ws + 9963520);  // 524,288
  float* hF0 = (float*)(ws + 10487808);          //    524,288
  float* hF1 = (float*)(ws + 11012096);          //    524,288
  _Float16* xiC = (_Float16*)(ws + 11536384);    //  Tc * 786,432
  const size_t fixed = 11536384;

  int Tc = 512;
  while (Tc > 1 && fixed + (size_t)Tc * 786432 > ws_size) Tc >>= 1;

  hipMemsetAsync(hP0, 0, 262144, stream);
  hipMemsetAsync(rel, 0, 526336, stream);        // rel + done
  hipMemsetAsync(hF0, 0, 524288, stream);
  pack_w_kernel<<<768, 256, 0, stream>>>(Wi, WiP, 16);
  pack_w_kernel<<<1536, 256, 0, stream>>>(Wh, WhP, 32);

  int dev = 0;
  (void)hipGetDevice(&dev);
  int ncu = 0;
  (void)hipDeviceGetAttribute(&ncu, hipDeviceAttributeMultiprocessorCount, dev);
  bool fused_ok = (ncu >= 256);

  if (fused_ok) {
    (void)hipFuncSetAttribute((const void*)gru_fused,
                              hipFuncAttributeMaxDynamicSharedMemorySize, 159744);
    (void)hipGetLastError();  // clear any sticky error
    gru_fused<<<dim3(256), dim3(256), 159744, stream>>>(x, WiP, WhP, bi, bh, hP0, hP1,
                                                        rel, done, out);
    if (hipGetLastError() != hipSuccess) fused_ok = false;
  }

  if (!fused_ok) {
    _Float16* hP[2] = {hP0, hP1};
    float* hF[2] = {hF0, hF1};
    const int nChunks = Tdim / Tc;
    for (int c = 0; c < nChunks; ++c) {
      int tbase = c * Tc;
      gemm_xi_kernel<<<dim3(Tc * 2, 24), 256, 0, stream>>>(x, WiP, bi, xiC, tbase);
      for (int tl = 0; tl < Tc; ++tl) {
        const int t = tbase + tl;
        float* dstF = (t == Tdim - 1) ? out : hF[(t + 1) & 1];
        gru_step_kernel<<<dim3(64, 2), 256, 0, stream>>>(WhP, hP[t & 1], hF[t & 1], xiC, bh,
                                                         dstF, hP[(t + 1) & 1], tl);
      }
    }
  }
}